// Round 2
// 69.666 us; speedup vs baseline: 1.0530x; 1.0530x over previous
//
#include <hip/hip_runtime.h>

// BitGatConv collapses algebraically:
//   coefs = softmax(scores, axis=1)  =>  sum_j coefs[i,j,c] == 1
//   vals[i,c] = sum_j coefs[i,j,c] * nhs[i,c] = nhs[i,c]
// so output == nodes_ft @ weight. One [1536x256]@[256x64] fp32 GEMM.
//
// v2 (resubmit after GPUAcquisitionTimeout — never benched): v1 launched only
// 384 waves (1.5/CU) -> latency-bound on L2/HBM loads with 64 CUs idle. Here
// the K dimension is split 8x inside the block and partials are combined
// through an 8 KiB LDS tree:
//   block = 512 threads = 4 rows x 16 col-quads x 8 k-chunks
//   grid  = 384 blocks  -> 3072 waves = 12 waves/CU (8x more TLP)
// Per thread: 8 fully-unrolled k-groups (1 A float4 + 4 W float4 each) ->
// ~40 independent loads in flight, 128 FMAs. No atomics, deterministic.

#define N_NODES 1536
#define IN_CH 256
#define HC 64
#define KS 8                   // K-split factor
#define ROWS 4                 // rows per block
#define KCHUNK (IN_CH / KS)    // 32 k's per split
#define BLOCK (ROWS * 16 * KS) // 512 threads

__global__ __launch_bounds__(BLOCK, 4) void nhs_gemm(const float* __restrict__ A,
                                                     const float* __restrict__ W,
                                                     float* __restrict__ out) {
    const int cq = threadIdx.x & 15;               // col-quad 0..15
    const int r  = (threadIdx.x >> 4) & (ROWS - 1);// row-in-block 0..3
    const int ks = threadIdx.x >> 6;               // k-chunk 0..7 (wave-uniform)
    const int row = blockIdx.x * ROWS + r;

    const float* a = A + row * IN_CH + ks * KCHUNK;
    const float* w = W + (cq << 2) + ks * KCHUNK * HC;

    float4 acc = make_float4(0.f, 0.f, 0.f, 0.f);
#pragma unroll
    for (int k = 0; k < KCHUNK; k += 4) {
        const float4 av = *(const float4*)(a + k);
        const float4 w0 = *(const float4*)(w + (k + 0) * HC);
        const float4 w1 = *(const float4*)(w + (k + 1) * HC);
        const float4 w2 = *(const float4*)(w + (k + 2) * HC);
        const float4 w3 = *(const float4*)(w + (k + 3) * HC);
        acc.x = fmaf(av.w, w3.x, fmaf(av.z, w2.x, fmaf(av.y, w1.x, fmaf(av.x, w0.x, acc.x))));
        acc.y = fmaf(av.w, w3.y, fmaf(av.z, w2.y, fmaf(av.y, w1.y, fmaf(av.x, w0.y, acc.y))));
        acc.z = fmaf(av.w, w3.z, fmaf(av.z, w2.z, fmaf(av.y, w1.z, fmaf(av.x, w0.z, acc.z))));
        acc.w = fmaf(av.w, w3.w, fmaf(av.z, w2.w, fmaf(av.y, w1.w, fmaf(av.x, w0.w, acc.w))));
    }

    // Combine the 8 K-split partials through LDS (8 KiB). Each wave (fixed ks)
    // writes a contiguous 1 KiB stripe; reduction reads are contiguous b128.
    __shared__ float4 red[KS][ROWS * 16];
    red[ks][(r << 4) | cq] = acc;
    __syncthreads();

    if (threadIdx.x < ROWS * 16) {
        float4 s = red[0][threadIdx.x];
#pragma unroll
        for (int i = 1; i < KS; ++i) {
            const float4 t = red[i][threadIdx.x];
            s.x += t.x; s.y += t.y; s.z += t.z; s.w += t.w;
        }
        const int rr = threadIdx.x >> 4;
        const int cc = threadIdx.x & 15;
        *(float4*)(out + (blockIdx.x * ROWS + rr) * HC + (cc << 2)) = s;
    }
}

extern "C" void kernel_launch(void* const* d_in, const int* in_sizes, int n_in,
                              void* d_out, int out_size, void* d_ws, size_t ws_size,
                              hipStream_t stream) {
    // setup_inputs order: nodes_ft, adj_bias_mat, weight, conv_weight1, conv_weight2
    const float* nodes_ft = (const float*)d_in[0];
    const float* weight   = (const float*)d_in[2];
    float* out = (float*)d_out;

    nhs_gemm<<<N_NODES / ROWS, BLOCK, 0, stream>>>(nodes_ft, weight, out);
}